// Round 1
// baseline (290.115 us; speedup 1.0000x reference)
//
#include <hip/hip_runtime.h>

#define B_ 32
#define N_ 64
#define F_ 128
#define E_ 4032
#define H_ 4
#define D_ 64

// ws layout (floats):
//  s_fwd  [B*N*H]      @ 0        (8192)
//  s_bwd  [B*N*H]      @ 8192     (8192)
//  u_src  [B*N*H*D]    @ 16384    (524288)
//  u_tgt  [B*N*H*D]    @ 540672   (524288)
//  v_soc  [B*N*H*D]    @ 1064960  (524288)
// total 1589248 floats = 6.36 MB

// K1: per 8 nodes: v_proj = v_self @ W_proj.T  (kept in LDS only),
//     s_fwd/s_bwd = leaky(v_proj . a)/500,  u_src/u_tgt = v_proj @ We1 halves.
__global__ __launch_bounds__(256) void k_proj(
    const float* __restrict__ v_self, const float* __restrict__ W_proj,
    const float* __restrict__ a_fwd, const float* __restrict__ a_bwd,
    const float* __restrict__ We1,
    float* __restrict__ s_fwd, float* __restrict__ s_bwd,
    float* __restrict__ u_src, float* __restrict__ u_tgt)
{
    const int t = threadIdx.x;
    const int h = t >> 6, d = t & 63;
    const int node0 = blockIdx.x * 8;

    __shared__ float vrow[8][128];
    __shared__ float vp[8][256];
    __shared__ float We1T[128][65];   // +1 pad: conflict-free transposed load & read

    for (int idx = t; idx < 8 * 128; idx += 256)
        vrow[idx >> 7][idx & 127] = v_self[(size_t)node0 * 128 + idx];
    for (int idx = t; idx < 64 * 128; idx += 256) {
        int dd = idx >> 7, k = idx & 127;        // coalesced global read
        We1T[k][dd] = We1[idx];                  // stride-65 LDS write: conflict-free
    }
    __syncthreads();

    // v_proj row: thread t owns output column t (= h*64+d) for all 8 nodes
    float acc[8];
#pragma unroll
    for (int nn = 0; nn < 8; ++nn) acc[nn] = 0.f;
    const float4* wp4 = (const float4*)(W_proj + (size_t)t * 128);
#pragma unroll 4
    for (int q = 0; q < 32; ++q) {
        float4 w = wp4[q];
#pragma unroll
        for (int nn = 0; nn < 8; ++nn) {
            float4 v = *(const float4*)&vrow[nn][q * 4];
            acc[nn] += w.x * v.x + w.y * v.y + w.z * v.z + w.w * v.w;
        }
    }
    const float af = a_fwd[t], ab = a_bwd[t];   // a_fwd[h][d] with t = h*64+d
#pragma unroll
    for (int nn = 0; nn < 8; ++nn) {
        vp[nn][t] = acc[nn];
        float pf = acc[nn] * af;
        float pb = acc[nn] * ab;
#pragma unroll
        for (int m = 1; m < 64; m <<= 1) {
            pf += __shfl_xor(pf, m);
            pb += __shfl_xor(pb, m);
        }
        if (d == 0) {
            float sf = (pf >= 0.f ? pf : 0.2f * pf) * (1.f / 500.f);
            float sb = (pb >= 0.f ? pb : 0.2f * pb) * (1.f / 500.f);
            s_fwd[(node0 + nn) * 4 + h] = sf;
            s_bwd[(node0 + nn) * 4 + h] = sb;
        }
    }
    __syncthreads();

    // u_src[d] = sum_k vp_h[k]*We1[d][k];  u_tgt[d] = sum_k vp_h[k]*We1[d][64+k]
    float us[8], ut[8];
#pragma unroll
    for (int nn = 0; nn < 8; ++nn) { us[nn] = 0.f; ut[nn] = 0.f; }
#pragma unroll 4
    for (int k = 0; k < 64; ++k) {
        float w1 = We1T[k][d];
        float w2 = We1T[64 + k][d];
#pragma unroll
        for (int nn = 0; nn < 8; ++nn) {
            float v = vp[nn][h * 64 + k];       // wave-uniform broadcast
            us[nn] += v * w1;
            ut[nn] += v * w2;
        }
    }
#pragma unroll
    for (int nn = 0; nn < 8; ++nn) {
        size_t base = ((size_t)(node0 + nn) * 4 + h) * 64 + d;
        u_src[base] = us[nn];
        u_tgt[base] = ut[nn];
    }
}

// K2: one block per (b, receiver j); wave = head. Loop senders i:
//   alpha -> hidden = relu(aij*u_src_i + aji*u_tgt_j + be1) -> e_cg = hidden@We2.T + be2
//   v_soc[b,j,h,:] += aij*e_cg ; write alpha_ij[b,e,h]
__global__ __launch_bounds__(256) void k_edge(
    const float* __restrict__ s_fwd, const float* __restrict__ s_bwd,
    const float* __restrict__ u_src, const float* __restrict__ u_tgt,
    const float* __restrict__ We2, const float* __restrict__ be1,
    const float* __restrict__ be2,
    float* __restrict__ v_soc, float* __restrict__ out_alpha)
{
    const int t = threadIdx.x;
    const int h = t >> 6, d = t & 63;
    const int blk = blockIdx.x;
    const int b = blk >> 6, j = blk & 63;

    __shared__ float We2T[64][65];
    __shared__ float hid[4][64];

    for (int idx = t; idx < 64 * 64; idx += 256) {
        int dd = idx >> 6, k = idx & 63;         // coalesced global read
        We2T[k][dd] = We2[idx];                  // stride-65 write: conflict-free
    }
    __syncthreads();

    float w2[64];                                // We2 row d in VGPRs
#pragma unroll
    for (int k = 0; k < 64; ++k) w2[k] = We2T[k][d];

    const float ut  = u_tgt[((size_t)(b * 64 + j) * 4 + h) * 64 + d];
    const float be1d = be1[d];
    const float be2d = be2[d];
    const float sbj = s_bwd[(b * 64 + j) * 4 + h];

    float vs = 0.f;
    for (int i = 0; i < 64; ++i) {
        if (i == j) continue;                    // uniform across block
        float sfi = s_fwd[(b * 64 + i) * 4 + h];
        float m = fmaxf(sfi, sbj);
        float eij = __expf(__expf(sfi - m));
        float eji = __expf(__expf(sbj - m));
        float inv = 1.f / (eij + eji);
        float aij = eij * inv;
        float aji = eji * inv;

        float usv = u_src[((size_t)(b * 64 + i) * 4 + h) * 64 + d];
        float hp = aij * usv + aji * ut + be1d;
        hid[h][d] = hp > 0.f ? hp : 0.f;
        __syncthreads();

        float ec = be2d;
        const float4* h4 = (const float4*)hid[h];
#pragma unroll
        for (int k4 = 0; k4 < 16; ++k4) {
            float4 hv = h4[k4];
            ec += w2[4 * k4 + 0] * hv.x + w2[4 * k4 + 1] * hv.y
                + w2[4 * k4 + 2] * hv.z + w2[4 * k4 + 3] * hv.w;
        }
        vs += aij * ec;

        if (d == 0) {
            int e = i * 63 + (j > i ? j - 1 : j);
            out_alpha[((size_t)b * E_ + e) * H_ + h] = aij;
        }
        __syncthreads();
    }
    v_soc[((size_t)(b * 64 + j) * 4 + h) * 64 + d] = vs;
}

// K3: per node: x1 = relu(vs@Wv1.T+bv1); x2 = relu(x1@Wv2.T+bv2); out = x2@Wv3.T+bv3
__global__ __launch_bounds__(256) void k_nodemlp(
    const float* __restrict__ v_soc,
    const float* __restrict__ Wv1, const float* __restrict__ bv1,
    const float* __restrict__ Wv2, const float* __restrict__ bv2,
    const float* __restrict__ Wv3, const float* __restrict__ bv3,
    float* __restrict__ v_out)
{
    const int t = threadIdx.x;
    const int node = blockIdx.x;

    __shared__ float vs[256];     // [h][d]
    __shared__ float x1[512];     // [h][f]
    __shared__ float x2[512];     // [h][f]

    vs[t] = v_soc[(size_t)node * 256 + t];
    __syncthreads();

#pragma unroll
    for (int it = 0; it < 2; ++it) {
        int o = it * 256 + t;
        int h = o >> 7, f = o & 127;
        float acc = bv1[f];
        const float4* w4 = (const float4*)(Wv1 + (size_t)f * 64);
        const float4* v4 = (const float4*)(vs + h * 64);
#pragma unroll
        for (int q = 0; q < 16; ++q) {
            float4 w = w4[q], v = v4[q];
            acc += w.x * v.x + w.y * v.y + w.z * v.z + w.w * v.w;
        }
        x1[o] = acc > 0.f ? acc : 0.f;
    }
    __syncthreads();

#pragma unroll
    for (int it = 0; it < 2; ++it) {
        int o = it * 256 + t;
        int h = o >> 7, f = o & 127;
        float acc = bv2[f];
        const float4* w4 = (const float4*)(Wv2 + (size_t)f * 128);
        const float4* v4 = (const float4*)(x1 + h * 128);
#pragma unroll
        for (int q = 0; q < 32; ++q) {
            float4 w = w4[q], v = v4[q];
            acc += w.x * v.x + w.y * v.y + w.z * v.z + w.w * v.w;
        }
        x2[o] = acc > 0.f ? acc : 0.f;
    }
    __syncthreads();

    {
        int h = t >> 6, dd = t & 63;
        float acc = bv3[dd];
        const float4* w4 = (const float4*)(Wv3 + (size_t)dd * 128);
        const float4* v4 = (const float4*)(x2 + h * 128);
#pragma unroll
        for (int q = 0; q < 32; ++q) {
            float4 w = w4[q], v = v4[q];
            acc += w.x * v.x + w.y * v.y + w.z * v.z + w.w * v.w;
        }
        v_out[(size_t)node * 256 + t] = acc;   // t = h*64+d -> concat heads
    }
}

extern "C" void kernel_launch(void* const* d_in, const int* in_sizes, int n_in,
                              void* d_out, int out_size, void* d_ws, size_t ws_size,
                              hipStream_t stream) {
    (void)in_sizes; (void)n_in; (void)out_size; (void)ws_size;
    const float* v_self = (const float*)d_in[0];
    // d_in[1] = rel_rec, d_in[2] = rel_send: one-hot of the fixed fully-connected
    // edge list (i-major, j skipping i) -> indices computed arithmetically.
    const float* W_proj = (const float*)d_in[3];
    const float* a_fwd  = (const float*)d_in[4];
    const float* a_bwd  = (const float*)d_in[5];
    const float* We1    = (const float*)d_in[6];
    const float* be1    = (const float*)d_in[7];
    const float* We2    = (const float*)d_in[8];
    const float* be2    = (const float*)d_in[9];
    const float* Wv1    = (const float*)d_in[10];
    const float* bv1    = (const float*)d_in[11];
    const float* Wv2    = (const float*)d_in[12];
    const float* bv2    = (const float*)d_in[13];
    const float* Wv3    = (const float*)d_in[14];
    const float* bv3    = (const float*)d_in[15];

    float* ws    = (float*)d_ws;
    float* s_fwd = ws;
    float* s_bwd = ws + 8192;
    float* u_src = ws + 16384;
    float* u_tgt = ws + 16384 + 524288;
    float* v_soc = ws + 16384 + 2 * 524288;

    float* v_out = (float*)d_out;
    float* alpha = v_out + (size_t)B_ * N_ * H_ * D_;

    hipLaunchKernelGGL(k_proj, dim3(B_ * N_ / 8), dim3(256), 0, stream,
                       v_self, W_proj, a_fwd, a_bwd, We1, s_fwd, s_bwd, u_src, u_tgt);
    hipLaunchKernelGGL(k_edge, dim3(B_ * N_), dim3(256), 0, stream,
                       s_fwd, s_bwd, u_src, u_tgt, We2, be1, be2, v_soc, alpha);
    hipLaunchKernelGGL(k_nodemlp, dim3(B_ * N_), dim3(256), 0, stream,
                       v_soc, Wv1, bv1, Wv2, bv2, Wv3, bv3, v_out);
}

// Round 2
// 106.061 us; speedup vs baseline: 2.7354x; 2.7354x over previous
//
#include <hip/hip_runtime.h>

#define B_ 32
#define N_ 64
#define F_ 128
#define E_ 4032
#define H_ 4
#define D_ 64

// ws layout (floats):
//  s_fwd  [B*N*H]      @ 0        (8192)
//  s_bwd  [B*N*H]      @ 8192     (8192)
//  u_src  [B*N*H*D]    @ 16384    (524288)
//  u_tgt  [B*N*H*D]    @ 540672   (524288)
//  v_soc  [B*N*H*D]    @ 1064960  (524288)

// K1: per 4 nodes: v_proj = v_self @ W_proj.T (LDS only),
//     s_fwd/s_bwd = leaky(v_proj . a)/500,  u_src/u_tgt = v_proj @ We1 halves.
__global__ __launch_bounds__(256) void k_proj(
    const float* __restrict__ v_self, const float* __restrict__ W_proj,
    const float* __restrict__ a_fwd, const float* __restrict__ a_bwd,
    const float* __restrict__ We1,
    float* __restrict__ s_fwd, float* __restrict__ s_bwd,
    float* __restrict__ u_src, float* __restrict__ u_tgt)
{
    const int t = threadIdx.x;
    const int h = t >> 6, d = t & 63;
    const int node0 = blockIdx.x * 4;

    __shared__ float vrow[4][128];
    __shared__ float vp[4][256];
    __shared__ float We1T[128][65];   // +1 pad: conflict-free transposed access

    for (int idx = t; idx < 4 * 128; idx += 256)
        vrow[idx >> 7][idx & 127] = v_self[(size_t)node0 * 128 + idx];
    for (int idx = t; idx < 64 * 128; idx += 256) {
        int dd = idx >> 7, k = idx & 127;        // coalesced global read
        We1T[k][dd] = We1[idx];                  // stride-65 LDS write: conflict-free
    }
    __syncthreads();

    // thread t owns v_proj column t (= h*64+d) for 4 nodes
    float acc[4] = {0.f, 0.f, 0.f, 0.f};
    const float4* wp4 = (const float4*)(W_proj + (size_t)t * 128);
#pragma unroll 8
    for (int q = 0; q < 32; ++q) {
        float4 w = wp4[q];
#pragma unroll
        for (int nn = 0; nn < 4; ++nn) {
            float4 v = *(const float4*)&vrow[nn][q * 4];
            acc[nn] += w.x * v.x + w.y * v.y + w.z * v.z + w.w * v.w;
        }
    }
    const float af = a_fwd[t], ab = a_bwd[t];   // a[h][d] with t = h*64+d
#pragma unroll
    for (int nn = 0; nn < 4; ++nn) {
        vp[nn][t] = acc[nn];
        float pf = acc[nn] * af;
        float pb = acc[nn] * ab;
#pragma unroll
        for (int m = 1; m < 64; m <<= 1) {
            pf += __shfl_xor(pf, m);
            pb += __shfl_xor(pb, m);
        }
        if (d == 0) {
            float sf = (pf >= 0.f ? pf : 0.2f * pf) * (1.f / 500.f);
            float sb = (pb >= 0.f ? pb : 0.2f * pb) * (1.f / 500.f);
            s_fwd[(node0 + nn) * 4 + h] = sf;
            s_bwd[(node0 + nn) * 4 + h] = sb;
        }
    }
    __syncthreads();

    // u_src[d] = sum_k vp_h[k]*We1[d][k];  u_tgt[d] = sum_k vp_h[k]*We1[d][64+k]
    float us[4] = {0.f, 0.f, 0.f, 0.f}, ut[4] = {0.f, 0.f, 0.f, 0.f};
#pragma unroll 4
    for (int k = 0; k < 64; ++k) {
        float w1 = We1T[k][d];
        float w2 = We1T[64 + k][d];
#pragma unroll
        for (int nn = 0; nn < 4; ++nn) {
            float v = vp[nn][h * 64 + k];       // wave-uniform broadcast
            us[nn] += v * w1;
            ut[nn] += v * w2;
        }
    }
#pragma unroll
    for (int nn = 0; nn < 4; ++nn) {
        size_t base = ((size_t)(node0 + nn) * 4 + h) * 64 + d;
        u_src[base] = us[nn];
        u_tgt[base] = ut[nn];
    }
}

// K2: one block per (b, receiver j); wave = head, lane = d (and lane = i in phase 1).
// We2 commuted past the scatter-sum: g[k] = sum_i aij*relu(hid[i][k]);
// v_soc = g @ We2.T + (sum_i aij)*be2. Zero barriers in the sender loop.
__global__ __launch_bounds__(256) void k_edge(
    const float* __restrict__ s_fwd, const float* __restrict__ s_bwd,
    const float* __restrict__ u_src, const float* __restrict__ u_tgt,
    const float* __restrict__ We2, const float* __restrict__ be1,
    const float* __restrict__ be2,
    float* __restrict__ v_soc, float* __restrict__ out_alpha)
{
    const int t = threadIdx.x;
    const int h = t >> 6, d = t & 63;
    const int blk = blockIdx.x;
    const int b = blk >> 6, j = blk & 63;

    __shared__ float aij_s[4][64];   // [h][i]
    __shared__ float g_s[4][64];     // [h][k]
    __shared__ float sum_s[4];

    // Phase 1: lane = sender i, wave = head. aji = 1 - aij.
    {
        const int i = d;
        float sfi = s_fwd[(b * 64 + i) * 4 + h];
        float sbj = s_bwd[(b * 64 + j) * 4 + h];
        float m = fmaxf(sfi, sbj);
        float eij = __expf(__expf(sfi - m));
        float eji = __expf(__expf(sbj - m));
        float aij = eij / (eij + eji);
        if (i == j) aij = 0.f;                  // self-edge excluded
        aij_s[h][i] = aij;
        float sa = aij;
#pragma unroll
        for (int m2 = 1; m2 < 64; m2 <<= 1) sa += __shfl_xor(sa, m2);
        if (i == 0) sum_s[h] = sa;
        if (i != j) {
            int e = i * 63 + (j > i ? j - 1 : j);
            out_alpha[((size_t)b * E_ + e) * H_ + h] = aij;
        }
    }
    __syncthreads();

    // Phase 2: lane = k (= d). g[k] = sum_i aij*relu(aij*(us-ut) + (ut+be1)).
    const float utv = u_tgt[((size_t)(b * 64 + j) * 4 + h) * 64 + d];
    const float ub  = utv + be1[d];
    const float* usrc = u_src + ((size_t)(b * 64) * 4 + h) * 64 + d;
    float g = 0.f;
#pragma unroll 8
    for (int i = 0; i < 64; ++i) {
        float a = aij_s[h][i];                  // wave-uniform broadcast
        float usv = usrc[i * 256];
        float hp = fmaf(a, usv - utv, ub);
        g = fmaf(a, fmaxf(hp, 0.f), g);
    }
    g_s[h][d] = g;
    __syncthreads();

    // Phase 3: vs[d] = sum_k g[k]*We2[d][k] + sum_aij*be2[d]
    float vs = sum_s[h] * be2[d];
    const float4* g4 = (const float4*)g_s[h];
    const float4* w4 = (const float4*)(We2 + (size_t)d * 64);
#pragma unroll
    for (int q = 0; q < 16; ++q) {
        float4 w = w4[q], gv = g4[q];
        vs += w.x * gv.x + w.y * gv.y + w.z * gv.z + w.w * gv.w;
    }
    v_soc[((size_t)(b * 64 + j) * 4 + h) * 64 + d] = vs;
}

// K3: 4 nodes per block; weight rows held in VGPRs and reused across nodes.
__global__ __launch_bounds__(256) void k_nodemlp(
    const float* __restrict__ v_soc,
    const float* __restrict__ Wv1, const float* __restrict__ bv1,
    const float* __restrict__ Wv2, const float* __restrict__ bv2,
    const float* __restrict__ Wv3, const float* __restrict__ bv3,
    float* __restrict__ v_out)
{
    const int t = threadIdx.x;
    const int node0 = blockIdx.x * 4;

    __shared__ float vs4[4][256];    // [nn][h*64+d]
    __shared__ float x1s[4][512];    // [nn][h*128+f]
    __shared__ float x2s[4][512];

    for (int idx = t; idx < 4 * 256; idx += 256)
        vs4[idx >> 8][idx & 255] = v_soc[(size_t)node0 * 256 + idx];
    __syncthreads();

    // Layer 1: 64 -> 128 (per head)
#pragma unroll
    for (int it = 0; it < 2; ++it) {
        int o = it * 256 + t;
        int h = o >> 7, f = o & 127;
        float4 w[16];
        const float4* wp = (const float4*)(Wv1 + (size_t)f * 64);
#pragma unroll
        for (int q = 0; q < 16; ++q) w[q] = wp[q];
        float bias = bv1[f];
#pragma unroll
        for (int nn = 0; nn < 4; ++nn) {
            float acc = bias;
            const float4* v4 = (const float4*)(vs4[nn] + h * 64);
#pragma unroll
            for (int q = 0; q < 16; ++q) {
                float4 v = v4[q];
                acc += w[q].x * v.x + w[q].y * v.y + w[q].z * v.z + w[q].w * v.w;
            }
            x1s[nn][o] = acc > 0.f ? acc : 0.f;
        }
    }
    __syncthreads();

    // Layer 2: 128 -> 128
#pragma unroll
    for (int it = 0; it < 2; ++it) {
        int o = it * 256 + t;
        int h = o >> 7, f = o & 127;
        float acc[4];
        float bias = bv2[f];
#pragma unroll
        for (int nn = 0; nn < 4; ++nn) acc[nn] = bias;
#pragma unroll
        for (int half = 0; half < 2; ++half) {
            float4 w[16];
            const float4* wp = (const float4*)(Wv2 + (size_t)f * 128 + half * 64);
#pragma unroll
            for (int q = 0; q < 16; ++q) w[q] = wp[q];
#pragma unroll
            for (int nn = 0; nn < 4; ++nn) {
                const float4* v4 = (const float4*)(x1s[nn] + h * 128 + half * 64);
#pragma unroll
                for (int q = 0; q < 16; ++q) {
                    float4 v = v4[q];
                    acc[nn] += w[q].x * v.x + w[q].y * v.y + w[q].z * v.z + w[q].w * v.w;
                }
            }
        }
#pragma unroll
        for (int nn = 0; nn < 4; ++nn)
            x2s[nn][o] = acc[nn] > 0.f ? acc[nn] : 0.f;
    }
    __syncthreads();

    // Layer 3: 128 -> 64; t = h*64+dd -> concat-heads output layout
    {
        int h = t >> 6, dd = t & 63;
        float acc[4];
        float bias = bv3[dd];
#pragma unroll
        for (int nn = 0; nn < 4; ++nn) acc[nn] = bias;
#pragma unroll
        for (int half = 0; half < 2; ++half) {
            float4 w[16];
            const float4* wp = (const float4*)(Wv3 + (size_t)dd * 128 + half * 64);
#pragma unroll
            for (int q = 0; q < 16; ++q) w[q] = wp[q];
#pragma unroll
            for (int nn = 0; nn < 4; ++nn) {
                const float4* v4 = (const float4*)(x2s[nn] + h * 128 + half * 64);
#pragma unroll
                for (int q = 0; q < 16; ++q) {
                    float4 v = v4[q];
                    acc[nn] += w[q].x * v.x + w[q].y * v.y + w[q].z * v.z + w[q].w * v.w;
                }
            }
        }
#pragma unroll
        for (int nn = 0; nn < 4; ++nn)
            v_out[(size_t)(node0 + nn) * 256 + t] = acc[nn];
    }
}

extern "C" void kernel_launch(void* const* d_in, const int* in_sizes, int n_in,
                              void* d_out, int out_size, void* d_ws, size_t ws_size,
                              hipStream_t stream) {
    (void)in_sizes; (void)n_in; (void)out_size; (void)ws_size;
    const float* v_self = (const float*)d_in[0];
    // d_in[1] = rel_rec, d_in[2] = rel_send: one-hot of the fixed fully-connected
    // edge list (i-major, j skipping i) -> indices computed arithmetically.
    const float* W_proj = (const float*)d_in[3];
    const float* a_fwd  = (const float*)d_in[4];
    const float* a_bwd  = (const float*)d_in[5];
    const float* We1    = (const float*)d_in[6];
    const float* be1    = (const float*)d_in[7];
    const float* We2    = (const float*)d_in[8];
    const float* be2    = (const float*)d_in[9];
    const float* Wv1    = (const float*)d_in[10];
    const float* bv1    = (const float*)d_in[11];
    const float* Wv2    = (const float*)d_in[12];
    const float* bv2    = (const float*)d_in[13];
    const float* Wv3    = (const float*)d_in[14];
    const float* bv3    = (const float*)d_in[15];

    float* ws    = (float*)d_ws;
    float* s_fwd = ws;
    float* s_bwd = ws + 8192;
    float* u_src = ws + 16384;
    float* u_tgt = ws + 16384 + 524288;
    float* v_soc = ws + 16384 + 2 * 524288;

    float* v_out = (float*)d_out;
    float* alpha = v_out + (size_t)B_ * N_ * H_ * D_;

    hipLaunchKernelGGL(k_proj, dim3(B_ * N_ / 4), dim3(256), 0, stream,
                       v_self, W_proj, a_fwd, a_bwd, We1, s_fwd, s_bwd, u_src, u_tgt);
    hipLaunchKernelGGL(k_edge, dim3(B_ * N_), dim3(256), 0, stream,
                       s_fwd, s_bwd, u_src, u_tgt, We2, be1, be2, v_soc, alpha);
    hipLaunchKernelGGL(k_nodemlp, dim3(B_ * N_ / 4), dim3(256), 0, stream,
                       v_soc, Wv1, bv1, Wv2, bv2, Wv3, bv3, v_out);
}

// Round 3
// 32.880 us; speedup vs baseline: 8.8234x; 3.2257x over previous
//
#include <hip/hip_runtime.h>

#define B_ 32
#define N_ 64
#define F_ 128
#define E_ 4032
#define H_ 4
#define D_ 64

typedef __bf16 bf16x8 __attribute__((ext_vector_type(8)));
typedef __bf16 bf16x4 __attribute__((ext_vector_type(4)));
typedef float  f32x4  __attribute__((ext_vector_type(4)));

// ws layout (float offsets):
//  s_fwd  @0        (8192)      s_bwd @8192 (8192)     suma @16384 (8192)
//  wb     @24576    (128)
//  M1bf   @24704    (4096f = 8192 bf16)   [128][64]
//  Wv2bf  @28800    (8192f = 16384 bf16)  [128][128]
//  Wv3bf  @36992    (4096f = 8192 bf16)   [64][128]
//  Wpbf   @41088    (16384f = 32768 bf16) [256][128]
//  We1bf  @57472    (4096f = 8192 bf16)   [2][64][64]
//  u_src  @61568    (262144f = 524288 bf16) [8192][64]
//  u_tgt  @323712   (262144f)
//  g      @585856   (524288f fp32) [8192][64]
// end 1110144 floats (4.44 MB, under round-1 high-water 6.36 MB)

// K0: M1 = Wv1@We2 (bf16), wb = Wv1@be2, and bf16 conversions of all weights.
__global__ __launch_bounds__(256) void k_prep(
    const float* __restrict__ Wv1, const float* __restrict__ We2,
    const float* __restrict__ be2, const float* __restrict__ W_proj,
    const float* __restrict__ Wv2, const float* __restrict__ Wv3,
    const float* __restrict__ We1,
    float* __restrict__ wb, __bf16* __restrict__ M1bf,
    __bf16* __restrict__ Wpbf, __bf16* __restrict__ Wv2bf,
    __bf16* __restrict__ Wv3bf, __bf16* __restrict__ We1bf)
{
    const int t = threadIdx.x;
    const int gid = blockIdx.x * 256 + t;          // 0..8191
    const int f = gid >> 6, k = gid & 63;

    float acc = 0.f;
    for (int d = 0; d < 64; ++d)
        acc += Wv1[f * 64 + d] * We2[d * 64 + k];  // Wv1 row wave-uniform
    M1bf[gid] = (__bf16)acc;

    float p = Wv1[f * 64 + k] * be2[k];
#pragma unroll
    for (int m = 1; m < 64; m <<= 1) p += __shfl_xor(p, m);
    if (k == 0) wb[f] = p;

#pragma unroll
    for (int i = 0; i < 4; ++i) Wpbf[gid * 4 + i] = (__bf16)W_proj[gid * 4 + i];
    Wv2bf[gid]        = (__bf16)Wv2[gid];
    Wv2bf[gid + 8192] = (__bf16)Wv2[gid + 8192];
    Wv3bf[gid]        = (__bf16)Wv3[gid];
    {   // We1bf[half][d][k] = We1[d][half*64+k]
        int half = gid >> 12, dd = (gid >> 6) & 63, kk = gid & 63;
        We1bf[gid] = (__bf16)We1[dd * 128 + half * 64 + kk];
    }
}

// K1 (MFMA): 8 nodes/block. P = v_self@W_proj^T (wave = head), scores from acc
// registers, then U = Phat@We1half^T (u_src/u_tgt, bf16 out).
__global__ __launch_bounds__(256) void k_proj(
    const float* __restrict__ v_self, const __bf16* __restrict__ Wpbf,
    const __bf16* __restrict__ We1bf,
    const float* __restrict__ a_fwd, const float* __restrict__ a_bwd,
    float* __restrict__ s_fwd, float* __restrict__ s_bwd,
    __bf16* __restrict__ u_src, __bf16* __restrict__ u_tgt)
{
    const int t = threadIdx.x;
    const int w = t >> 6, l = t & 63;
    const int q = l >> 4, lr = l & 15;
    const int node0 = blockIdx.x * 8;

    __shared__ __bf16 Av[16 * 136];      // [16 rows][128+8] (rows 8-15 zero)
    __shared__ __bf16 P_lds[8 * 288];    // [node][h][72]

    {   // stage v_self rows -> bf16; zero pad rows
        int row = t >> 5, c0 = (t & 31) * 4;
        float4 v = *(const float4*)(v_self + (size_t)(node0 + row) * 128 + c0);
        bf16x4 bv; bv[0]=(__bf16)v.x; bv[1]=(__bf16)v.y; bv[2]=(__bf16)v.z; bv[3]=(__bf16)v.w;
        *(bf16x4*)&Av[row * 136 + c0] = bv;
        bf16x4 z = {};
        *(bf16x4*)&Av[(row + 8) * 136 + c0] = z;
    }
    __syncthreads();

    // P GEMM: rows = 8 nodes (of 16-tile), cols w*64..+63, K = 128
    f32x4 acc[4] = {};
#pragma unroll
    for (int ks = 0; ks < 4; ++ks) {
        bf16x8 a = *(const bf16x8*)&Av[lr * 136 + ks * 32 + q * 8];
#pragma unroll
        for (int ct = 0; ct < 4; ++ct) {
            bf16x8 b = *(const bf16x8*)(Wpbf + (size_t)(w * 64 + ct * 16 + lr) * 128 + ks * 32 + q * 8);
            acc[ct] = __builtin_amdgcn_mfma_f32_16x16x32_bf16(a, b, acc[ct], 0, 0, 0);
        }
    }

    // scores: s = leaky(P . a_h)/500, reduced across the 16-lane col groups
    {
        float pf[4] = {0,0,0,0}, pb[4] = {0,0,0,0};
#pragma unroll
        for (int ct = 0; ct < 4; ++ct) {
            float af = a_fwd[w * 64 + ct * 16 + lr];
            float ab = a_bwd[w * 64 + ct * 16 + lr];
#pragma unroll
            for (int r = 0; r < 4; ++r) { pf[r] += acc[ct][r] * af; pb[r] += acc[ct][r] * ab; }
        }
#pragma unroll
        for (int m = 1; m < 16; m <<= 1) {
#pragma unroll
            for (int r = 0; r < 4; ++r) { pf[r] += __shfl_xor(pf[r], m); pb[r] += __shfl_xor(pb[r], m); }
        }
        if (lr == 0 && q < 2) {
#pragma unroll
            for (int r = 0; r < 4; ++r) {
                int node = q * 4 + r;
                float x = pf[r]; x = (x >= 0.f ? x : 0.2f * x) * 0.002f;
                float y = pb[r]; y = (y >= 0.f ? y : 0.2f * y) * 0.002f;
                s_fwd[(node0 + node) * 4 + w] = x;
                s_bwd[(node0 + node) * 4 + w] = y;
            }
        }
    }
    if (q < 2) {    // P rows 0..7 -> LDS bf16
#pragma unroll
        for (int ct = 0; ct < 4; ++ct)
#pragma unroll
            for (int r = 0; r < 4; ++r)
                P_lds[(q * 4 + r) * 288 + w * 72 + ct * 16 + lr] = (__bf16)acc[ct][r];
    }
    __syncthreads();

    // U GEMM: rows rr = node*4+h (32), wave: rt = w&1 row-tile, mm = w>>1 (us/ut)
    const int rt = w & 1, mm = w >> 1;
    const __bf16* Wh = We1bf + mm * 4096;
    const int rr = rt * 16 + lr, an = rr >> 2, ah = rr & 3;
    f32x4 uacc[4] = {};
#pragma unroll
    for (int ks = 0; ks < 2; ++ks) {
        bf16x8 a = *(const bf16x8*)&P_lds[an * 288 + ah * 72 + ks * 32 + q * 8];
#pragma unroll
        for (int ct = 0; ct < 4; ++ct) {
            bf16x8 b = *(const bf16x8*)(Wh + (ct * 16 + lr) * 64 + ks * 32 + q * 8);
            uacc[ct] = __builtin_amdgcn_mfma_f32_16x16x32_bf16(a, b, uacc[ct], 0, 0, 0);
        }
    }
    __bf16* up = (mm == 0) ? u_src : u_tgt;
#pragma unroll
    for (int ct = 0; ct < 4; ++ct)
#pragma unroll
        for (int r = 0; r < 4; ++r) {
            int row = rt * 16 + q * 4 + r;       // (node,h) packed
            up[(size_t)(node0 * 4 + row) * 64 + ct * 16 + lr] = (__bf16)uacc[ct][r];
        }
}

// K2: block (b, receiver j); g[k] = sum_i aij*relu(aij*(us-ut)+ut+be1); suma.
__global__ __launch_bounds__(256) void k_edge(
    const float* __restrict__ s_fwd, const float* __restrict__ s_bwd,
    const __bf16* __restrict__ u_src, const __bf16* __restrict__ u_tgt,
    const float* __restrict__ be1,
    float* __restrict__ g_out, float* __restrict__ suma_out)
{
    const int t = threadIdx.x;
    const int h = t >> 6, d = t & 63;
    const int b = blockIdx.x >> 6, j = blockIdx.x & 63;

    __shared__ float aij_s[4][64];

    {
        const int i = d;
        float sfi = s_fwd[(b * 64 + i) * 4 + h];
        float sbj = s_bwd[(b * 64 + j) * 4 + h];
        float m = fmaxf(sfi, sbj);
        float eij = __expf(__expf(sfi - m));
        float eji = __expf(__expf(sbj - m));
        float aij = eij / (eij + eji);
        if (i == j) aij = 0.f;
        aij_s[h][i] = aij;
        float sa = aij;
#pragma unroll
        for (int m2 = 1; m2 < 64; m2 <<= 1) sa += __shfl_xor(sa, m2);
        if (i == 0) suma_out[(b * 64 + j) * 4 + h] = sa;
    }
    __syncthreads();

    const float utv = (float)u_tgt[((size_t)(b * 64 + j) * 4 + h) * 64 + d];
    const float ub  = utv + be1[d];
    const __bf16* usp = u_src + ((size_t)(b * 64) * 4 + h) * 64 + d;
    float g = 0.f;
#pragma unroll 8
    for (int i = 0; i < 64; ++i) {
        float a = aij_s[h][i];
        float usv = (float)usp[(size_t)i * 256];
        float hp = fmaf(a, usv - utv, ub);
        g = fmaf(a, fmaxf(hp, 0.f), g);
    }
    g_out[((size_t)(b * 64 + j) * 4 + h) * 64 + d] = g;
}

// K3: alpha with coalesced writes; block = (b, sender i), thread = (jj, h).
__global__ __launch_bounds__(256) void k_alpha(
    const float* __restrict__ s_fwd, const float* __restrict__ s_bwd,
    float* __restrict__ out_alpha)
{
    const int t = threadIdx.x;
    if (t >= 252) return;
    const int b = blockIdx.x >> 6, i = blockIdx.x & 63;
    const int jj = t >> 2, h = t & 3;
    const int j = jj + (jj >= i ? 1 : 0);
    float sfi = s_fwd[(b * 64 + i) * 4 + h];
    float sbj = s_bwd[(b * 64 + j) * 4 + h];
    float m = fmaxf(sfi, sbj);
    float eij = __expf(__expf(sfi - m));
    float eji = __expf(__expf(sbj - m));
    out_alpha[((size_t)b * E_ + i * 63 + jj) * 4 + h] = eij / (eij + eji);
}

// K4 (MFMA): node MLP over rows r=(bn,h): g->relu(M1,+suma*wb+bv1)->relu(Wv2)->Wv3.
__global__ __launch_bounds__(256) void k_mlp(
    const float* __restrict__ g_in, const float* __restrict__ suma_in,
    const __bf16* __restrict__ M1bf, const float* __restrict__ wb,
    const float* __restrict__ bv1,
    const __bf16* __restrict__ Wv2bf, const float* __restrict__ bv2,
    const __bf16* __restrict__ Wv3bf, const float* __restrict__ bv3,
    float* __restrict__ v_out)
{
    const int t = threadIdx.x;
    const int w = t >> 6, l = t & 63;
    const int q = l >> 4, lr = l & 15;
    const int rows0 = blockIdx.x * 32;

    __shared__ __bf16 G_lds[32 * 72];
    __shared__ __bf16 X1[32 * 136];
    __shared__ __bf16 X2[32 * 136];
    __shared__ float  suma_l[32];

    {   // stage g fp32 -> bf16 LDS
        int row = t >> 3, c0 = (t & 7) * 8;
        float4 v0 = *(const float4*)(g_in + (size_t)(rows0 + row) * 64 + c0);
        float4 v1 = *(const float4*)(g_in + (size_t)(rows0 + row) * 64 + c0 + 4);
        bf16x8 bv;
        bv[0]=(__bf16)v0.x; bv[1]=(__bf16)v0.y; bv[2]=(__bf16)v0.z; bv[3]=(__bf16)v0.w;
        bv[4]=(__bf16)v1.x; bv[5]=(__bf16)v1.y; bv[6]=(__bf16)v1.z; bv[7]=(__bf16)v1.w;
        *(bf16x8*)&G_lds[row * 72 + c0] = bv;
        if (t < 32) suma_l[t] = suma_in[rows0 + t];
    }
    __syncthreads();

    const int rt = w & 1, ch = w >> 1;   // row-tile, col-half

    // layer 1: cols ch*64..+63, K=64
    f32x4 acc1[4] = {};
#pragma unroll
    for (int ks = 0; ks < 2; ++ks) {
        bf16x8 a = *(const bf16x8*)&G_lds[(rt * 16 + lr) * 72 + ks * 32 + q * 8];
#pragma unroll
        for (int ct = 0; ct < 4; ++ct) {
            bf16x8 b = *(const bf16x8*)(M1bf + (size_t)(ch * 64 + ct * 16 + lr) * 64 + ks * 32 + q * 8);
            acc1[ct] = __builtin_amdgcn_mfma_f32_16x16x32_bf16(a, b, acc1[ct], 0, 0, 0);
        }
    }
    float sml[4];
#pragma unroll
    for (int r = 0; r < 4; ++r) sml[r] = suma_l[rt * 16 + q * 4 + r];
#pragma unroll
    for (int ct = 0; ct < 4; ++ct) {
        int f = ch * 64 + ct * 16 + lr;
        float wbf = wb[f], b1 = bv1[f];
#pragma unroll
        for (int r = 0; r < 4; ++r) {
            float x = acc1[ct][r] + sml[r] * wbf + b1;
            X1[(rt * 16 + q * 4 + r) * 136 + f] = (__bf16)fmaxf(x, 0.f);
        }
    }
    __syncthreads();

    // layer 2: cols ch*64..+63, K=128
    f32x4 acc2[4] = {};
#pragma unroll
    for (int ks = 0; ks < 4; ++ks) {
        bf16x8 a = *(const bf16x8*)&X1[(rt * 16 + lr) * 136 + ks * 32 + q * 8];
#pragma unroll
        for (int ct = 0; ct < 4; ++ct) {
            bf16x8 b = *(const bf16x8*)(Wv2bf + (size_t)(ch * 64 + ct * 16 + lr) * 128 + ks * 32 + q * 8);
            acc2[ct] = __builtin_amdgcn_mfma_f32_16x16x32_bf16(a, b, acc2[ct], 0, 0, 0);
        }
    }
#pragma unroll
    for (int ct = 0; ct < 4; ++ct) {
        int f = ch * 64 + ct * 16 + lr;
        float b2 = bv2[f];
#pragma unroll
        for (int r = 0; r < 4; ++r) {
            float x = acc2[ct][r] + b2;
            X2[(rt * 16 + q * 4 + r) * 136 + f] = (__bf16)fmaxf(x, 0.f);
        }
    }
    __syncthreads();

    // layer 3: cols ch*32..+31 (N=64), K=128; write fp32 out
    f32x4 acc3[2] = {};
#pragma unroll
    for (int ks = 0; ks < 4; ++ks) {
        bf16x8 a = *(const bf16x8*)&X2[(rt * 16 + lr) * 136 + ks * 32 + q * 8];
#pragma unroll
        for (int ct = 0; ct < 2; ++ct) {
            bf16x8 b = *(const bf16x8*)(Wv3bf + (size_t)(ch * 32 + ct * 16 + lr) * 128 + ks * 32 + q * 8);
            acc3[ct] = __builtin_amdgcn_mfma_f32_16x16x32_bf16(a, b, acc3[ct], 0, 0, 0);
        }
    }
#pragma unroll
    for (int ct = 0; ct < 2; ++ct) {
        int dd = ch * 32 + ct * 16 + lr;
        float b3 = bv3[dd];
#pragma unroll
        for (int r = 0; r < 4; ++r)
            v_out[(size_t)(rows0 + rt * 16 + q * 4 + r) * 64 + dd] = acc3[ct][r] + b3;
    }
}

extern "C" void kernel_launch(void* const* d_in, const int* in_sizes, int n_in,
                              void* d_out, int out_size, void* d_ws, size_t ws_size,
                              hipStream_t stream) {
    (void)in_sizes; (void)n_in; (void)out_size; (void)ws_size;
    const float* v_self = (const float*)d_in[0];
    const float* W_proj = (const float*)d_in[3];
    const float* a_fwd  = (const float*)d_in[4];
    const float* a_bwd  = (const float*)d_in[5];
    const float* We1    = (const float*)d_in[6];
    const float* be1    = (const float*)d_in[7];
    const float* We2    = (const float*)d_in[8];
    const float* be2    = (const float*)d_in[9];
    const float* Wv1    = (const float*)d_in[10];
    const float* bv1    = (const float*)d_in[11];
    const float* Wv2    = (const float*)d_in[12];
    const float* bv2    = (const float*)d_in[13];
    const float* Wv3    = (const float*)d_in[14];
    const float* bv3    = (const float*)d_in[15];

    float* ws = (float*)d_ws;
    float*  s_fwd = ws;
    float*  s_bwd = ws + 8192;
    float*  suma  = ws + 16384;
    float*  wb    = ws + 24576;
    __bf16* M1bf  = (__bf16*)(ws + 24704);
    __bf16* Wv2bf = (__bf16*)(ws + 28800);
    __bf16* Wv3bf = (__bf16*)(ws + 36992);
    __bf16* Wpbf  = (__bf16*)(ws + 41088);
    __bf16* We1bf = (__bf16*)(ws + 57472);
    __bf16* u_src = (__bf16*)(ws + 61568);
    __bf16* u_tgt = (__bf16*)(ws + 323712);
    float*  g     = ws + 585856;

    float* v_out = (float*)d_out;
    float* alpha = v_out + (size_t)B_ * N_ * H_ * D_;

    hipLaunchKernelGGL(k_prep, dim3(32), dim3(256), 0, stream,
                       Wv1, We2, be2, W_proj, Wv2, Wv3, We1,
                       wb, M1bf, Wpbf, Wv2bf, Wv3bf, We1bf);
    hipLaunchKernelGGL(k_proj, dim3(B_ * N_ / 8), dim3(256), 0, stream,
                       v_self, Wpbf, We1bf, a_fwd, a_bwd, s_fwd, s_bwd, u_src, u_tgt);
    hipLaunchKernelGGL(k_edge, dim3(B_ * N_), dim3(256), 0, stream,
                       s_fwd, s_bwd, u_src, u_tgt, be1, g, suma);
    hipLaunchKernelGGL(k_alpha, dim3(B_ * N_), dim3(256), 0, stream,
                       s_fwd, s_bwd, alpha);
    hipLaunchKernelGGL(k_mlp, dim3(B_ * N_ * H_ / 32), dim3(256), 0, stream,
                       g, suma, M1bf, wb, bv1, Wv2bf, bv2, Wv3bf, bv3, v_out);
}

// Round 4
// 29.764 us; speedup vs baseline: 9.7471x; 1.1047x over previous
//
#include <hip/hip_runtime.h>

#define B_ 32
#define N_ 64
#define F_ 128
#define E_ 4032
#define H_ 4
#define D_ 64

typedef __bf16 bf16x8 __attribute__((ext_vector_type(8)));
typedef __bf16 bf16x4 __attribute__((ext_vector_type(4)));
typedef float  f32x4  __attribute__((ext_vector_type(4)));

// ws layout (float offsets):
//  s_fwd @0 (8192)   s_bwd @8192 (8192)   suma @16384 (8192)
//  wb    @24576 (128)
//  M1bf  @24704 (4096f = 8192 bf16)   [128][64]
//  Wv2bf @28800 (8192f = 16384 bf16)  [128][128]
//  Wv3bf @36992 (4096f = 8192 bf16)   [64][128]
//  u_src @61568 (262144f = 524288 bf16) [8192][64]
//  u_tgt @323712 (262144f)
//  g_bf  @585856 (262144f = 524288 bf16) [8192][64]

// K1 (MFMA): 8 nodes/block. P = v_self@W_proj^T (wave = head), scores from acc
// registers, then U = Phat@We1half^T (u_src/u_tgt, bf16). Weights converted
// fp32->bf16 inline (each B-fragment used once; no reuse to stage).
__global__ __launch_bounds__(256) void k_proj(
    const float* __restrict__ v_self, const float* __restrict__ W_proj,
    const float* __restrict__ We1,
    const float* __restrict__ a_fwd, const float* __restrict__ a_bwd,
    float* __restrict__ s_fwd, float* __restrict__ s_bwd,
    __bf16* __restrict__ u_src, __bf16* __restrict__ u_tgt)
{
    const int t = threadIdx.x;
    const int w = t >> 6, l = t & 63;
    const int q = l >> 4, lr = l & 15;
    const int node0 = blockIdx.x * 8;

    __shared__ __bf16 Av[16 * 136];      // [16 rows][128+8] (rows 8-15 zero)
    __shared__ __bf16 P_lds[8 * 288];    // [node][h][72]

    {   // stage v_self rows -> bf16; zero pad rows
        int row = t >> 5, c0 = (t & 31) * 4;
        float4 v = *(const float4*)(v_self + (size_t)(node0 + row) * 128 + c0);
        bf16x4 bv; bv[0]=(__bf16)v.x; bv[1]=(__bf16)v.y; bv[2]=(__bf16)v.z; bv[3]=(__bf16)v.w;
        *(bf16x4*)&Av[row * 136 + c0] = bv;
        bf16x4 z = {};
        *(bf16x4*)&Av[(row + 8) * 136 + c0] = z;
    }
    __syncthreads();

    // P GEMM: rows = 8 nodes (16-tile), cols w*64..+63, K = 128
    f32x4 acc[4] = {};
#pragma unroll
    for (int ks = 0; ks < 4; ++ks) {
        bf16x8 a = *(const bf16x8*)&Av[lr * 136 + ks * 32 + q * 8];
#pragma unroll
        for (int ct = 0; ct < 4; ++ct) {
            const float4* wr = (const float4*)(W_proj + (size_t)(w * 64 + ct * 16 + lr) * 128 + ks * 32 + q * 8);
            float4 w0 = wr[0], w1 = wr[1];
            bf16x8 b;
            b[0]=(__bf16)w0.x; b[1]=(__bf16)w0.y; b[2]=(__bf16)w0.z; b[3]=(__bf16)w0.w;
            b[4]=(__bf16)w1.x; b[5]=(__bf16)w1.y; b[6]=(__bf16)w1.z; b[7]=(__bf16)w1.w;
            acc[ct] = __builtin_amdgcn_mfma_f32_16x16x32_bf16(a, b, acc[ct], 0, 0, 0);
        }
    }

    // scores: s = leaky(P . a_h)/500, reduced across 16-lane col groups
    {
        float pf[4] = {0,0,0,0}, pb[4] = {0,0,0,0};
#pragma unroll
        for (int ct = 0; ct < 4; ++ct) {
            float af = a_fwd[w * 64 + ct * 16 + lr];
            float ab = a_bwd[w * 64 + ct * 16 + lr];
#pragma unroll
            for (int r = 0; r < 4; ++r) { pf[r] += acc[ct][r] * af; pb[r] += acc[ct][r] * ab; }
        }
#pragma unroll
        for (int m = 1; m < 16; m <<= 1) {
#pragma unroll
            for (int r = 0; r < 4; ++r) { pf[r] += __shfl_xor(pf[r], m); pb[r] += __shfl_xor(pb[r], m); }
        }
        if (lr == 0 && q < 2) {
#pragma unroll
            for (int r = 0; r < 4; ++r) {
                int node = q * 4 + r;
                float x = pf[r]; x = (x >= 0.f ? x : 0.2f * x) * 0.002f;
                float y = pb[r]; y = (y >= 0.f ? y : 0.2f * y) * 0.002f;
                s_fwd[(node0 + node) * 4 + w] = x;
                s_bwd[(node0 + node) * 4 + w] = y;
            }
        }
    }
    if (q < 2) {    // P rows 0..7 -> LDS bf16
#pragma unroll
        for (int ct = 0; ct < 4; ++ct)
#pragma unroll
            for (int r = 0; r < 4; ++r)
                P_lds[(q * 4 + r) * 288 + w * 72 + ct * 16 + lr] = (__bf16)acc[ct][r];
    }
    __syncthreads();

    // U GEMM: rows rr = node*4+h (32), wave: rt = w&1 row-tile, mm = w>>1 (us/ut)
    const int rt = w & 1, mm = w >> 1;
    const int rr = rt * 16 + lr, an = rr >> 2, ah = rr & 3;
    f32x4 uacc[4] = {};
#pragma unroll
    for (int ks = 0; ks < 2; ++ks) {
        bf16x8 a = *(const bf16x8*)&P_lds[an * 288 + ah * 72 + ks * 32 + q * 8];
#pragma unroll
        for (int ct = 0; ct < 4; ++ct) {
            const float4* wr = (const float4*)(We1 + (size_t)(ct * 16 + lr) * 128 + mm * 64 + ks * 32 + q * 8);
            float4 w0 = wr[0], w1 = wr[1];
            bf16x8 b;
            b[0]=(__bf16)w0.x; b[1]=(__bf16)w0.y; b[2]=(__bf16)w0.z; b[3]=(__bf16)w0.w;
            b[4]=(__bf16)w1.x; b[5]=(__bf16)w1.y; b[6]=(__bf16)w1.z; b[7]=(__bf16)w1.w;
            uacc[ct] = __builtin_amdgcn_mfma_f32_16x16x32_bf16(a, b, uacc[ct], 0, 0, 0);
        }
    }
    __bf16* up = (mm == 0) ? u_src : u_tgt;
#pragma unroll
    for (int ct = 0; ct < 4; ++ct)
#pragma unroll
        for (int r = 0; r < 4; ++r) {
            int row = rt * 16 + q * 4 + r;       // (node,h) packed
            up[(size_t)(node0 * 4 + row) * 64 + ct * 16 + lr] = (__bf16)uacc[ct][r];
        }
}

// K2: blocks 0..2047: (b, x) — receiver-role g/suma for j=x, sender-role
// coalesced alpha for i=x. Blocks 2048..2079: weight prep for k_mlp
// (M1 = Wv1@We2, wb = Wv1@be2, bf16 conversions of Wv2/Wv3).
__global__ __launch_bounds__(256) void k_edge(
    const float* __restrict__ s_fwd, const float* __restrict__ s_bwd,
    const __bf16* __restrict__ u_src, const __bf16* __restrict__ u_tgt,
    const float* __restrict__ be1,
    const float* __restrict__ Wv1, const float* __restrict__ We2,
    const float* __restrict__ be2, const float* __restrict__ Wv2,
    const float* __restrict__ Wv3,
    __bf16* __restrict__ g_out, float* __restrict__ suma_out,
    float* __restrict__ out_alpha,
    __bf16* __restrict__ M1bf, float* __restrict__ wb,
    __bf16* __restrict__ Wv2bf, __bf16* __restrict__ Wv3bf)
{
    const int t = threadIdx.x;
    const int blk = blockIdx.x;

    if (blk >= B_ * N_) {                       // ---- prep role ----
        const int pid = (blk - B_ * N_) * 256 + t;   // 0..8191
        const int f = pid >> 6, k = pid & 63;
        float acc = 0.f;
        for (int d = 0; d < 64; ++d)
            acc += Wv1[f * 64 + d] * We2[d * 64 + k];   // Wv1 wave-uniform
        M1bf[pid] = (__bf16)acc;
        float p = Wv1[f * 64 + k] * be2[k];
#pragma unroll
        for (int m = 1; m < 64; m <<= 1) p += __shfl_xor(p, m);
        if (k == 0) wb[f] = p;
        Wv2bf[pid]        = (__bf16)Wv2[pid];
        Wv2bf[pid + 8192] = (__bf16)Wv2[pid + 8192];
        Wv3bf[pid]        = (__bf16)Wv3[pid];
        return;
    }

    const int h = t >> 6, d = t & 63;
    const int b = blk >> 6, x = blk & 63;
    const int j = x;

    __shared__ float aij_s[4][64];

    // sender-role alpha (i = x): fully coalesced writes
    if (t < 252) {
        const int jj = t >> 2, h2 = t & 3;
        const int j2 = jj + (jj >= x ? 1 : 0);
        float sfi = s_fwd[(b * 64 + x) * 4 + h2];
        float sbj = s_bwd[(b * 64 + j2) * 4 + h2];
        float m = fmaxf(sfi, sbj);
        float eij = __expf(__expf(sfi - m));
        float eji = __expf(__expf(sbj - m));
        out_alpha[((size_t)b * E_ + x * 63 + jj) * 4 + h2] = eij / (eij + eji);
    }

    // receiver-role phase 1: lane = sender i, wave = head
    {
        const int i = d;
        float sfi = s_fwd[(b * 64 + i) * 4 + h];
        float sbj = s_bwd[(b * 64 + j) * 4 + h];
        float m = fmaxf(sfi, sbj);
        float eij = __expf(__expf(sfi - m));
        float eji = __expf(__expf(sbj - m));
        float aij = eij / (eij + eji);
        if (i == j) aij = 0.f;
        aij_s[h][i] = aij;
        float sa = aij;
#pragma unroll
        for (int m2 = 1; m2 < 64; m2 <<= 1) sa += __shfl_xor(sa, m2);
        if (i == 0) suma_out[(b * 64 + j) * 4 + h] = sa;
    }
    __syncthreads();

    // phase 2: lane = k (= d). g[k] = sum_i aij*relu(aij*(us-ut)+ut+be1)
    const float utv = (float)u_tgt[((size_t)(b * 64 + j) * 4 + h) * 64 + d];
    const float ub  = utv + be1[d];
    const __bf16* usp = u_src + ((size_t)(b * 64) * 4 + h) * 64 + d;
    float g = 0.f;
#pragma unroll 8
    for (int i = 0; i < 64; ++i) {
        float a = aij_s[h][i];
        float usv = (float)usp[(size_t)i * 256];
        float hp = fmaf(a, usv - utv, ub);
        g = fmaf(a, fmaxf(hp, 0.f), g);
    }
    g_out[((size_t)(b * 64 + j) * 4 + h) * 64 + d] = (__bf16)g;
}

// K3 (MFMA): node MLP over rows r=(bn,h): g->relu(M1,+suma*wb+bv1)->relu(Wv2)->Wv3.
// A-fragments of g read straight from global bf16 (no LDS staging).
__global__ __launch_bounds__(256) void k_mlp(
    const __bf16* __restrict__ g_bf, const float* __restrict__ suma_in,
    const __bf16* __restrict__ M1bf, const float* __restrict__ wb,
    const float* __restrict__ bv1,
    const __bf16* __restrict__ Wv2bf, const float* __restrict__ bv2,
    const __bf16* __restrict__ Wv3bf, const float* __restrict__ bv3,
    float* __restrict__ v_out)
{
    const int t = threadIdx.x;
    const int w = t >> 6, l = t & 63;
    const int q = l >> 4, lr = l & 15;
    const int rows0 = blockIdx.x * 32;

    __shared__ __bf16 X1[32 * 136];
    __shared__ __bf16 X2[32 * 136];

    const int rt = w & 1, ch = w >> 1;   // row-tile, col-half

    // layer 1: cols ch*64..+63, K=64
    f32x4 acc1[4] = {};
#pragma unroll
    for (int ks = 0; ks < 2; ++ks) {
        bf16x8 a = *(const bf16x8*)(g_bf + (size_t)(rows0 + rt * 16 + lr) * 64 + ks * 32 + q * 8);
#pragma unroll
        for (int ct = 0; ct < 4; ++ct) {
            bf16x8 b = *(const bf16x8*)(M1bf + (size_t)(ch * 64 + ct * 16 + lr) * 64 + ks * 32 + q * 8);
            acc1[ct] = __builtin_amdgcn_mfma_f32_16x16x32_bf16(a, b, acc1[ct], 0, 0, 0);
        }
    }
    float sml[4];
#pragma unroll
    for (int r = 0; r < 4; ++r) sml[r] = suma_in[rows0 + rt * 16 + q * 4 + r];
#pragma unroll
    for (int ct = 0; ct < 4; ++ct) {
        int f = ch * 64 + ct * 16 + lr;
        float wbf = wb[f], b1 = bv1[f];
#pragma unroll
        for (int r = 0; r < 4; ++r) {
            float xv = acc1[ct][r] + sml[r] * wbf + b1;
            X1[(rt * 16 + q * 4 + r) * 136 + f] = (__bf16)fmaxf(xv, 0.f);
        }
    }
    __syncthreads();

    // layer 2: cols ch*64..+63, K=128
    f32x4 acc2[4] = {};
#pragma unroll
    for (int ks = 0; ks < 4; ++ks) {
        bf16x8 a = *(const bf16x8*)&X1[(rt * 16 + lr) * 136 + ks * 32 + q * 8];
#pragma unroll
        for (int ct = 0; ct < 4; ++ct) {
            bf16x8 b = *(const bf16x8*)(Wv2bf + (size_t)(ch * 64 + ct * 16 + lr) * 128 + ks * 32 + q * 8);
            acc2[ct] = __builtin_amdgcn_mfma_f32_16x16x32_bf16(a, b, acc2[ct], 0, 0, 0);
        }
    }
#pragma unroll
    for (int ct = 0; ct < 4; ++ct) {
        int f = ch * 64 + ct * 16 + lr;
        float b2 = bv2[f];
#pragma unroll
        for (int r = 0; r < 4; ++r) {
            float xv = acc2[ct][r] + b2;
            X2[(rt * 16 + q * 4 + r) * 136 + f] = (__bf16)fmaxf(xv, 0.f);
        }
    }
    __syncthreads();

    // layer 3: cols ch*32..+31 (N=64), K=128; fp32 out
    f32x4 acc3[2] = {};
#pragma unroll
    for (int ks = 0; ks < 4; ++ks) {
        bf16x8 a = *(const bf16x8*)&X2[(rt * 16 + lr) * 136 + ks * 32 + q * 8];
#pragma unroll
        for (int ct = 0; ct < 2; ++ct) {
            bf16x8 b = *(const bf16x8*)(Wv3bf + (size_t)(ch * 32 + ct * 16 + lr) * 128 + ks * 32 + q * 8);
            acc3[ct] = __builtin_amdgcn_mfma_f32_16x16x32_bf16(a, b, acc3[ct], 0, 0, 0);
        }
    }
#pragma unroll
    for (int ct = 0; ct < 2; ++ct) {
        int dd = ch * 32 + ct * 16 + lr;
        float b3 = bv3[dd];
#pragma unroll
        for (int r = 0; r < 4; ++r)
            v_out[(size_t)(rows0 + rt * 16 + q * 4 + r) * 64 + dd] = acc3[ct][r] + b3;
    }
}

extern "C" void kernel_launch(void* const* d_in, const int* in_sizes, int n_in,
                              void* d_out, int out_size, void* d_ws, size_t ws_size,
                              hipStream_t stream) {
    (void)in_sizes; (void)n_in; (void)out_size; (void)ws_size;
    const float* v_self = (const float*)d_in[0];
    const float* W_proj = (const float*)d_in[3];
    const float* a_fwd  = (const float*)d_in[4];
    const float* a_bwd  = (const float*)d_in[5];
    const float* We1    = (const float*)d_in[6];
    const float* be1    = (const float*)d_in[7];
    const float* We2    = (const float*)d_in[8];
    const float* be2    = (const float*)d_in[9];
    const float* Wv1    = (const float*)d_in[10];
    const float* bv1    = (const float*)d_in[11];
    const float* Wv2    = (const float*)d_in[12];
    const float* bv2    = (const float*)d_in[13];
    const float* Wv3    = (const float*)d_in[14];
    const float* bv3    = (const float*)d_in[15];

    float* ws = (float*)d_ws;
    float*  s_fwd = ws;
    float*  s_bwd = ws + 8192;
    float*  suma  = ws + 16384;
    float*  wb    = ws + 24576;
    __bf16* M1bf  = (__bf16*)(ws + 24704);
    __bf16* Wv2bf = (__bf16*)(ws + 28800);
    __bf16* Wv3bf = (__bf16*)(ws + 36992);
    __bf16* u_src = (__bf16*)(ws + 61568);
    __bf16* u_tgt = (__bf16*)(ws + 323712);
    __bf16* g_bf  = (__bf16*)(ws + 585856);

    float* v_out = (float*)d_out;
    float* alpha = v_out + (size_t)B_ * N_ * H_ * D_;

    hipLaunchKernelGGL(k_proj, dim3(B_ * N_ / 8), dim3(256), 0, stream,
                       v_self, W_proj, We1, a_fwd, a_bwd, s_fwd, s_bwd, u_src, u_tgt);
    hipLaunchKernelGGL(k_edge, dim3(B_ * N_ + 32), dim3(256), 0, stream,
                       s_fwd, s_bwd, u_src, u_tgt, be1, Wv1, We2, be2, Wv2, Wv3,
                       g_bf, suma, alpha, M1bf, wb, Wv2bf, Wv3bf);
    hipLaunchKernelGGL(k_mlp, dim3(B_ * N_ * H_ / 32), dim3(256), 0, stream,
                       g_bf, suma, M1bf, wb, bv1, Wv2bf, bv2, Wv3bf, bv3, v_out);
}